// Round 4
// baseline (272.332 us; speedup 1.0000x reference)
//
#include <hip/hip_runtime.h>
#include <hip/hip_bf16.h>
#include <type_traits>

// ---------------------------------------------------------------------------
// Problem constants
//   x: (8,128,128,256) f32   z: (8,64,64,256) f32   mask: (1,8,8,8,256,64) int
//   Wq (256,256) bq(256)  Wkv (256,512) bkv(512)  Wo (256,256) bo(256)
//   rel_table (900,8) f32   out: (8,128,128,256) f32
// ---------------------------------------------------------------------------

typedef __attribute__((ext_vector_type(8))) short short8v;     // MFMA bf16 frag (4 VGPR)
typedef __attribute__((ext_vector_type(4))) float f32x4;       // MFMA acc
typedef __attribute__((ext_vector_type(8))) unsigned short ushort8v;
typedef __attribute__((ext_vector_type(4))) unsigned short ushort4v;

#define DEV __device__ __forceinline__

DEV unsigned short f2bf(float f) {               // round-to-nearest-even f32->bf16
    union { float f; unsigned u; } v; v.f = f;
    unsigned r = v.u + 0x7FFFu + ((v.u >> 16) & 1u);
    return (unsigned short)(r >> 16);
}

DEV short8v cvt_f32x8(const float4 lo, const float4 hi) {      // 8 f32 -> 8 bf16 (RNE)
    union U { __hip_bfloat162 h[4]; short8v s; } u;
    u.h[0] = __float22bfloat162_rn(float2{lo.x, lo.y});
    u.h[1] = __float22bfloat162_rn(float2{lo.z, lo.w});
    u.h[2] = __float22bfloat162_rn(float2{hi.x, hi.y});
    u.h[3] = __float22bfloat162_rn(float2{hi.z, hi.w});
    return u.s;
}

#define ATT_SCALE 0.17677669529663687f           // 1/sqrt(32)

// ---------------------------------------------------------------------------
// Prep kernels (unchanged)
// ---------------------------------------------------------------------------
__global__ void prep_weights(const float* __restrict__ Wq, const float* __restrict__ Wkv,
                             const float* __restrict__ Wo,
                             unsigned short* __restrict__ WqT, unsigned short* __restrict__ WkvT,
                             unsigned short* __restrict__ WoT) {
    int idx = blockIdx.x * 256 + threadIdx.x;            // 262144 total
    if (idx < 65536) {
        int n = idx >> 8, k = idx & 255;
        WqT[idx] = f2bf(Wq[k * 256 + n] * ATT_SCALE);
    } else if (idx < 196608) {
        int i = idx - 65536;
        int n = i >> 8, k = i & 255;
        WkvT[i] = f2bf(Wkv[k * 512 + n]);
    } else {
        int i = idx - 196608;
        int n = i >> 8, k = i & 255;
        WoT[i] = f2bf(Wo[k * 256 + n]);
    }
}

__global__ void prep_bias(const float* __restrict__ rel_table, const float* __restrict__ bq,
                          float* __restrict__ biasb, float* __restrict__ bqs) {
    int idx = blockIdx.x * 256 + threadIdx.x;
    if (idx < 131072) {
        int head = idx >> 14;
        int q = (idx >> 6) & 255;
        int k = idx & 63;
        int qi = q >> 4, qj = q & 15;
        int ki = k >> 3, kj = k & 7;
        int r0 = qi - 2 * ki + 14, r1 = qj - 2 * kj + 14;
        biasb[idx] = rel_table[(r0 * 30 + r1) * 8 + head];
    } else if (idx < 131328) {
        int i = idx - 131072;
        bqs[i] = bq[i] * ATT_SCALE;
    }
}

__global__ void prep_mask(const int* __restrict__ mask, unsigned long long* __restrict__ mp) {
    int idx = blockIdx.x * 256 + threadIdx.x;            // 131072 rows
    const int4* src = reinterpret_cast<const int4*>(mask + (size_t)idx * 64);
    unsigned long long bits = 0;
#pragma unroll
    for (int c = 0; c < 16; ++c) {
        int4 v = src[c];
        if (v.x) bits |= 1ull << (c * 4 + 0);
        if (v.y) bits |= 1ull << (c * 4 + 1);
        if (v.z) bits |= 1ull << (c * 4 + 2);
        if (v.w) bits |= 1ull << (c * 4 + 3);
    }
    mp[idx] = bits;
}

// ---------------------------------------------------------------------------
// GEMM v3 "stream": C[M][N] = A[M][K=256]*B + bias, B^T row-major bf16 [N][K].
// Block = 512 thr (8 waves, 4m x 2n of 64x64), block tile 256m x 128n.
// B panel [128n][256k] staged in LDS ONCE (kt-major [8][128][64B], slot-XOR
// swizzle) -> single barrier. A streamed global->reg (32B/lane/frag), f32
// converted in-reg via v_cvt_pk, 2-deep ping-pong prefetch. NO barriers in
// the K loop -> pure ILP/TLP streaming.
// ---------------------------------------------------------------------------
template <bool AF32, bool OUT_BF16>
__global__ __launch_bounds__(512) void gemm_stream(
    const void* __restrict__ Ain, const unsigned short* __restrict__ BT,
    const float* __restrict__ bias, void* __restrict__ Cout,
    int M, int N)
{
    __shared__ __align__(16) unsigned char Bs[65536];    // [8 kt][128 row][64 B]
    const float* Af = (const float*)Ain;
    const unsigned short* Ab = (const unsigned short*)Ain;

    const int tid = threadIdx.x;
    const int w = tid >> 6, lane = tid & 63, lr = lane & 15, lg = lane >> 4;
    const int mb = blockIdx.x * 256;
    const int nb = blockIdx.y * 128;
    const int wm = (w >> 1) * 64;                        // 4 m-waves
    const int wn = (w & 1) * 64;                         // 2 n-waves

    // ---- stage B panel once: thread -> 128B quarter-row ----
    {
        int row = tid >> 2, part = tid & 3;
        const unsigned short* src = BT + (size_t)(nb + row) * 256 + part * 64;
        int rsw = (row >> 1) & 3;
        ushort8v bv[8];
#pragma unroll
        for (int i = 0; i < 8; ++i)
            bv[i] = *reinterpret_cast<const ushort8v*>(src + i * 8);
#pragma unroll
        for (int h = 0; h < 2; ++h)
#pragma unroll
            for (int sl = 0; sl < 4; ++sl)
                *reinterpret_cast<ushort8v*>(
                    &Bs[(part * 2 + h) * 8192 + row * 64 + ((sl ^ rsw) << 4)]) = bv[h * 4 + sl];
    }
    __syncthreads();                                     // the ONLY barrier

    const int swzB = (lg ^ ((lr >> 1) & 3)) << 4;        // lane-constant read swizzle
    auto rdB = [&](int kt, int nt) -> short8v {
        return *reinterpret_cast<const short8v*>(
            &Bs[kt * 8192 + (wn + nt * 16 + lr) * 64 + swzB]);
    };

    f32x4 acc[4][4];
#pragma unroll
    for (int i = 0; i < 4; ++i)
#pragma unroll
        for (int j = 0; j < 4; ++j) acc[i][j] = {0.f, 0.f, 0.f, 0.f};

    if constexpr (AF32) {
        const float* Abase = Af + (size_t)(mb + wm + lr) * 256 + lg * 8;
        float4 aP[4][2], aQ[4][2];
        auto loadA = [&](float4 (&buf)[4][2], int kt) {
#pragma unroll
            for (int mt = 0; mt < 4; ++mt) {
                const float* p = Abase + mt * 4096 + kt * 32;
                buf[mt][0] = *reinterpret_cast<const float4*>(p);
                buf[mt][1] = *reinterpret_cast<const float4*>(p + 4);
            }
        };
        auto compute = [&](float4 (&buf)[4][2], int kt) {
            short8v af[4], bf[4];
#pragma unroll
            for (int mt = 0; mt < 4; ++mt) af[mt] = cvt_f32x8(buf[mt][0], buf[mt][1]);
#pragma unroll
            for (int nt = 0; nt < 4; ++nt) bf[nt] = rdB(kt, nt);
#pragma unroll
            for (int mt = 0; mt < 4; ++mt)
#pragma unroll
                for (int nt = 0; nt < 4; ++nt)
                    acc[mt][nt] = __builtin_amdgcn_mfma_f32_16x16x32_bf16(
                        af[mt], bf[nt], acc[mt][nt], 0, 0, 0);
        };
        loadA(aP, 0);
#pragma unroll
        for (int kk = 0; kk < 8; kk += 2) {
            if (kk + 1 < 8) loadA(aQ, kk + 1);
            compute(aP, kk);
            if (kk + 2 < 8) loadA(aP, kk + 2);
            compute(aQ, kk + 1);
        }
    } else {
        const unsigned short* Abase = Ab + (size_t)(mb + wm + lr) * 256 + lg * 8;
        short8v aP[4], aQ[4];
        auto loadA = [&](short8v (&buf)[4], int kt) {
#pragma unroll
            for (int mt = 0; mt < 4; ++mt)
                buf[mt] = *reinterpret_cast<const short8v*>(Abase + mt * 4096 + kt * 32);
        };
        auto compute = [&](short8v (&buf)[4], int kt) {
            short8v bf[4];
#pragma unroll
            for (int nt = 0; nt < 4; ++nt) bf[nt] = rdB(kt, nt);
#pragma unroll
            for (int mt = 0; mt < 4; ++mt)
#pragma unroll
                for (int nt = 0; nt < 4; ++nt)
                    acc[mt][nt] = __builtin_amdgcn_mfma_f32_16x16x32_bf16(
                        buf[mt], bf[nt], acc[mt][nt], 0, 0, 0);
        };
        loadA(aP, 0);
#pragma unroll
        for (int kk = 0; kk < 8; kk += 2) {
            if (kk + 1 < 8) loadA(aQ, kk + 1);
            compute(aP, kk);
            if (kk + 2 < 8) loadA(aP, kk + 2);
            compute(aQ, kk + 1);
        }
    }

    // ---- epilogue ----
#pragma unroll
    for (int mt = 0; mt < 4; ++mt)
#pragma unroll
        for (int nt = 0; nt < 4; ++nt)
#pragma unroll
            for (int j = 0; j < 4; ++j) {
                int row = mb + wm + mt * 16 + lg * 4 + j;
                int col = nb + wn + nt * 16 + lr;
                float v = acc[mt][nt][j] + bias[col];
                if constexpr (OUT_BF16)
                    ((unsigned short*)Cout)[(size_t)row * N + col] = f2bf(v);
                else
                    ((float*)Cout)[(size_t)row * N + col] = v;
            }
}

// ---------------------------------------------------------------------------
// Fused window attention (unchanged from R1/R2).
// ---------------------------------------------------------------------------
__global__ __launch_bounds__(256) void win_attn(
    unsigned short* __restrict__ Qbuf,            // [8*128*128, 256] bf16 (in/out)
    const unsigned short* __restrict__ KVbuf,     // [8*64*64, 512] bf16
    const unsigned long long* __restrict__ maskp, // [8][64][256] packed bits
    const float* __restrict__ biasb)              // [8][256][64]
{
    __shared__ __align__(16) unsigned char Pb[256 * 128];   // P, 64-wide XOR-swizzled
    __shared__ __align__(16) unsigned short Vt[32][72];     // V^T: [dk][key]

    const int tid = threadIdx.x;
    const int win = blockIdx.x, head = blockIdx.y, b = blockIdx.z;
    const int wi = win >> 3, wj = win & 7;
    const int w = tid >> 6, lane = tid & 63, lr = lane & 15, lg = lane >> 4;
    const int qb = w * 64;

    {
        int key = tid & 63, c = tid >> 6;
        int kr = (wi * 8 + (key >> 3) + 4) & 63;
        int kc = (wj * 8 + (key & 7) + 4) & 63;
        ushort8v v = *reinterpret_cast<const ushort8v*>(
            KVbuf + ((size_t)(b * 4096 + kr * 64 + kc)) * 512 + 256 + head * 32 + c * 8);
#pragma unroll
        for (int e = 0; e < 8; ++e) Vt[c * 8 + e][key] = v[e];
    }

    short8v qf[4], kf[4];
#pragma unroll
    for (int mt = 0; mt < 4; ++mt) {
        int q = qb + mt * 16 + lr;
        int gr = (wi * 16 + (q >> 4) + 8) & 127;
        int gc = (wj * 16 + (q & 15) + 8) & 127;
        qf[mt] = *reinterpret_cast<const short8v*>(
            Qbuf + ((size_t)(b * 16384 + gr * 128 + gc)) * 256 + head * 32 + lg * 8);
    }
#pragma unroll
    for (int nt = 0; nt < 4; ++nt) {
        int key = nt * 16 + lr;
        int kr = (wi * 8 + (key >> 3) + 4) & 63;
        int kc = (wj * 8 + (key & 7) + 4) & 63;
        kf[nt] = *reinterpret_cast<const short8v*>(
            KVbuf + ((size_t)(b * 4096 + kr * 64 + kc)) * 512 + head * 32 + lg * 8);
    }

    f32x4 s[4][4];
#pragma unroll
    for (int mt = 0; mt < 4; ++mt)
#pragma unroll
        for (int nt = 0; nt < 4; ++nt) s[mt][nt] = {0.f, 0.f, 0.f, 0.f};
    __builtin_amdgcn_s_setprio(1);
#pragma unroll
    for (int mt = 0; mt < 4; ++mt)
#pragma unroll
        for (int nt = 0; nt < 4; ++nt)
            s[mt][nt] = __builtin_amdgcn_mfma_f32_16x16x32_bf16(qf[mt], kf[nt], s[mt][nt], 0, 0, 0);
    __builtin_amdgcn_s_setprio(0);

    const unsigned long long* mrow = maskp + (size_t)(head * 64 + win) * 256;
#pragma unroll
    for (int mt = 0; mt < 4; ++mt) {
#pragma unroll
        for (int j = 0; j < 4; ++j) {
            int q = qb + mt * 16 + lg * 4 + j;
            unsigned long long mb = mrow[q];
            const float* brow = biasb + (size_t)(head * 256 + q) * 64;
            float v[4];
            float m = -3.0e38f;
#pragma unroll
            for (int nt = 0; nt < 4; ++nt) {
                int key = nt * 16 + lr;
                float sv = s[mt][nt][j] + brow[key];
                if ((mb >> key) & 1ull) sv = -1.0e9f;
                v[nt] = sv;
                m = fmaxf(m, sv);
            }
#pragma unroll
            for (int d = 1; d < 16; d <<= 1) m = fmaxf(m, __shfl_xor(m, d, 64));
            float sum = 0.f;
#pragma unroll
            for (int nt = 0; nt < 4; ++nt) { v[nt] = __expf(v[nt] - m); sum += v[nt]; }
#pragma unroll
            for (int d = 1; d < 16; d <<= 1) sum += __shfl_xor(sum, d, 64);
            float inv = 1.0f / sum;
            int sw = (q & 7) << 4;
#pragma unroll
            for (int nt = 0; nt < 4; ++nt) {
                int off = q * 128 + (((nt * 16 + lr) * 2) ^ sw);
                *reinterpret_cast<unsigned short*>(Pb + off) = f2bf(v[nt] * inv);
            }
        }
    }

    __syncthreads();

    f32x4 o[4][2];
#pragma unroll
    for (int mt = 0; mt < 4; ++mt)
#pragma unroll
        for (int nt = 0; nt < 2; ++nt) o[mt][nt] = {0.f, 0.f, 0.f, 0.f};
#pragma unroll
    for (int kc = 0; kc < 2; ++kc) {
        short8v pf[4], vf[2];
#pragma unroll
        for (int mt = 0; mt < 4; ++mt) {
            int row = qb + mt * 16 + lr;
            int coff = (kc * 64 + lg * 16) ^ ((row & 7) << 4);
            pf[mt] = *reinterpret_cast<const short8v*>(Pb + row * 128 + coff);
        }
#pragma unroll
        for (int nt = 0; nt < 2; ++nt)
            vf[nt] = *reinterpret_cast<const short8v*>(&Vt[nt * 16 + lr][kc * 32 + lg * 8]);
        __builtin_amdgcn_s_setprio(1);
#pragma unroll
        for (int mt = 0; mt < 4; ++mt)
#pragma unroll
            for (int nt = 0; nt < 2; ++nt)
                o[mt][nt] = __builtin_amdgcn_mfma_f32_16x16x32_bf16(pf[mt], vf[nt], o[mt][nt], 0, 0, 0);
        __builtin_amdgcn_s_setprio(0);
    }

#pragma unroll
    for (int mt = 0; mt < 4; ++mt)
#pragma unroll
        for (int j = 0; j < 4; ++j) {
            int q = qb + mt * 16 + lg * 4 + j;
            int gr = (wi * 16 + (q >> 4) + 8) & 127;
            int gc = (wj * 16 + (q & 15) + 8) & 127;
            unsigned short* dst =
                Qbuf + ((size_t)(b * 16384 + gr * 128 + gc)) * 256 + head * 32;
#pragma unroll
            for (int nt = 0; nt < 2; ++nt)
                dst[nt * 16 + lr] = f2bf(o[mt][nt][j]);
        }
}

// ---------------------------------------------------------------------------
extern "C" void kernel_launch(void* const* d_in, const int* in_sizes, int n_in,
                              void* d_out, int out_size, void* d_ws, size_t ws_size,
                              hipStream_t stream) {
    const float* x    = (const float*)d_in[0];
    const float* z    = (const float*)d_in[1];
    const int*   mask = (const int*)d_in[2];
    const float* Wq   = (const float*)d_in[3];
    const float* bq   = (const float*)d_in[4];
    const float* Wkv  = (const float*)d_in[5];
    const float* bkv  = (const float*)d_in[6];
    const float* Wo   = (const float*)d_in[7];
    const float* bo   = (const float*)d_in[8];
    const float* rel  = (const float*)d_in[9];
    float* out = (float*)d_out;

    // workspace layout (~103 MB)
    char* ws = (char*)d_ws;
    unsigned short*     Qbuf  = (unsigned short*)(ws);                 // 67,108,864 B
    unsigned short*     KVbuf = (unsigned short*)(ws + 67108864);      // 33,554,432 B
    unsigned short*     WqT   = (unsigned short*)(ws + 100663296);     //    131,072 B
    unsigned short*     WkvT  = (unsigned short*)(ws + 100794368);     //    262,144 B
    unsigned short*     WoT   = (unsigned short*)(ws + 101056512);     //    131,072 B
    float*              biasb = (float*)(ws + 101187584);              //    524,288 B
    unsigned long long* maskp = (unsigned long long*)(ws + 101711872); //  1,048,576 B
    float*              bqs   = (float*)(ws + 102760448);              //      1,024 B

    prep_weights<<<1024, 256, 0, stream>>>(Wq, Wkv, Wo, WqT, WkvT, WoT);
    prep_bias<<<513, 256, 0, stream>>>(rel, bq, biasb, bqs);
    prep_mask<<<512, 256, 0, stream>>>(mask, maskp);

    // Q = x @ (Wq*scale) + bq*scale  -> bf16 [131072, 256]
    gemm_stream<true, true><<<dim3(512, 2), 512, 0, stream>>>(
        (const void*)x, WqT, bqs, (void*)Qbuf, 131072, 256);
    // KV = z @ Wkv + bkv -> bf16 [32768, 512]
    gemm_stream<true, true><<<dim3(128, 4), 512, 0, stream>>>(
        (const void*)z, WkvT, bkv, (void*)KVbuf, 32768, 512);
    // fused window attention (in-place into Qbuf)
    win_attn<<<dim3(64, 8, 8), 256, 0, stream>>>(Qbuf, KVbuf, maskp, biasb);
    // out = attn @ Wo + bo -> f32
    gemm_stream<false, false><<<dim3(512, 2), 512, 0, stream>>>(
        (const void*)Qbuf, WoT, bo, (void*)out, 131072, 256);
}